// Round 4
// baseline (325.318 us; speedup 1.0000x reference)
//
#include <hip/hip_runtime.h>
#include <hip/hip_bf16.h>
#include <cmath>

// Problem constants
#define BB 2
#define TT 2048
#define CC 1024
#define HH 16
#define DD 64
#define ROWS (BB*TT)          // 4096
#define N1 (3*CC)             // 3072
#define EPS 1e-6f

using short8 = __attribute__((ext_vector_type(8))) short;
using f32x4  = __attribute__((ext_vector_type(4))) float;

__device__ __forceinline__ void gl_lds16(const __hip_bfloat16* g, unsigned short* l) {
    __builtin_amdgcn_global_load_lds(
        (const __attribute__((address_space(1))) unsigned int*)(g),
        (__attribute__((address_space(3))) unsigned int*)(l), 16, 0, 0);
}

__device__ __forceinline__ unsigned int bf16pair(float a, float b) {
    __hip_bfloat16 ha = (__hip_bfloat16)a, hb = (__hip_bfloat16)b;  // RNE
    unsigned short ua = *(unsigned short*)&ha, ub = *(unsigned short*)&hb;
    return (unsigned int)ua | ((unsigned int)ub << 16);
}

__device__ __forceinline__ float bf2f(unsigned short u) {
    unsigned int v = (unsigned int)u << 16;
    return *(float*)&v;
}

// ---------------------------------------------------------------- rope table
__global__ void rope_init(float* __restrict__ rope) {
    int idx = blockIdx.x * 256 + threadIdx.x;      // 0 .. T*32-1
    if (idx >= TT * 32) return;
    int t = idx >> 5, i = idx & 31;
    double freq = pow(10000.0, -(double)i / 32.0);
    float ang = (float)t * (float)freq;
    rope[idx * 2 + 0] = cosf(ang);
    rope[idx * 2 + 1] = sinf(ang);
}

// ------------------------------------------- row sum-of-squares + bf16 cast
__global__ void rowsq_cast(const float* __restrict__ X, float* __restrict__ xsq,
                           __hip_bfloat16* __restrict__ Xb) {
    int row = blockIdx.x;
    int t = threadIdx.x;
    const float* xr = X + (size_t)row * CC;
    __hip_bfloat16* br = Xb + (size_t)row * CC;
    float p = 0.f;
#pragma unroll
    for (int i = 0; i < 4; ++i) {
        float v = xr[t + i * 256];
        p += v * v;
        br[t + i * 256] = (__hip_bfloat16)v;
    }
    __shared__ float s[256];
    s[t] = p;
    __syncthreads();
    for (int off = 128; off > 0; off >>= 1) {
        if (t < off) s[t] += s[t + off];
        __syncthreads();
    }
    if (t == 0) xsq[row] = s[0];
}

// --------------------- transpose W (K x N fp32) -> Wt (N x K bf16) + col sq
__global__ void transpose_colsq(const float* __restrict__ W,
                                __hip_bfloat16* __restrict__ Wt,
                                float* __restrict__ wsq, int K, int N) {
    __shared__ unsigned short tile[64][65];
    int n0 = blockIdx.x * 64, k0 = blockIdx.y * 64;
    int c = threadIdx.x & 63, rg = threadIdx.x >> 6;
    float part = 0.f;
#pragma unroll
    for (int rr = 0; rr < 16; ++rr) {
        int r = rg + rr * 4;
        float f = W[(size_t)(k0 + r) * N + n0 + c];
        __hip_bfloat16 h = (__hip_bfloat16)f;
        tile[r][c] = *(unsigned short*)&h;
        part += f * f;
    }
    atomicAdd(&wsq[n0 + c], part);
    __syncthreads();
#pragma unroll
    for (int rr = 0; rr < 16; ++rr) {
        int r = rg + rr * 4;
        unsigned short u = tile[c][r];
        Wt[(size_t)(n0 + r) * K + k0 + c] = *(__hip_bfloat16*)&u;
    }
}

// ------------------- m97-style MFMA bf16 GEMM (TMxTN tile) with yat epilogue
template<int TM, int TN, typename OutT>
__global__ __launch_bounds__(256) void yat_gemm_big(
    const __hip_bfloat16* __restrict__ A,
    const __hip_bfloat16* __restrict__ Bt,
    const float* __restrict__ xsq, const float* __restrict__ wsq,
    const float* __restrict__ bias, OutT* __restrict__ C,
    int M, int N, int K, float scale) {
    constexpr int MT = TM / 32;
    constexpr int NT = TN / 32;
    constexpr int IA = TM / 64;
    constexpr int IB = TN / 64;
    __shared__ __align__(16) unsigned short As[TM * 32];
    __shared__ __align__(16) unsigned short Bs[TN * 32];
    int tid = threadIdx.x;
    int wave = tid >> 6, lane = tid & 63, quad = lane >> 4, l16 = lane & 15;
    int wr = wave >> 1, wc = wave & 1;
    int m0 = blockIdx.y * TM, n0 = blockIdx.x * TN;

    f32x4 acc[MT][NT];
#pragma unroll
    for (int mt = 0; mt < MT; ++mt)
#pragma unroll
        for (int nt = 0; nt < NT; ++nt) acc[mt][nt] = f32x4{0.f, 0.f, 0.f, 0.f};

    int lrow = lane >> 2, lk = (lane & 3) << 3;
    for (int k0 = 0; k0 < K; k0 += 32) {
        __syncthreads();
#pragma unroll
        for (int i = 0; i < IA; ++i)
            gl_lds16(A + (size_t)(m0 + (wave * IA + i) * 16 + lrow) * K + k0 + lk,
                     As + (wave * IA + i) * 512);
#pragma unroll
        for (int i = 0; i < IB; ++i)
            gl_lds16(Bt + (size_t)(n0 + (wave * IB + i) * 16 + lrow) * K + k0 + lk,
                     Bs + (wave * IB + i) * 512);
        __syncthreads();
        short8 af[MT], bf[NT];
#pragma unroll
        for (int mt = 0; mt < MT; ++mt)
            af[mt] = *(const short8*)(As + (wr * (TM / 2) + mt * 16 + l16) * 32 + quad * 8);
#pragma unroll
        for (int nt = 0; nt < NT; ++nt)
            bf[nt] = *(const short8*)(Bs + (wc * (TN / 2) + nt * 16 + l16) * 32 + quad * 8);
#pragma unroll
        for (int mt = 0; mt < MT; ++mt)
#pragma unroll
            for (int nt = 0; nt < NT; ++nt)
                acc[mt][nt] = __builtin_amdgcn_mfma_f32_16x16x32_bf16(af[mt], bf[nt], acc[mt][nt], 0, 0, 0);
    }
    int mb = m0 + wr * (TM / 2) + quad * 4;
#pragma unroll
    for (int nt = 0; nt < NT; ++nt) {
        int col = n0 + wc * (TN / 2) + nt * 16 + l16;
        float wq = wsq[col];
        float bs = bias[col];
#pragma unroll
        for (int mt = 0; mt < MT; ++mt) {
#pragma unroll
            for (int r = 0; r < 4; ++r) {
                int row = mb + mt * 16 + r;
                float dot = acc[mt][nt][r];
                float dist = xsq[row] + wq - 2.f * dot + EPS;
                C[(size_t)row * N + col] = (OutT)(dot * dot / dist * scale + bs);
            }
        }
    }
}

// -------------------------- prep: bf16 qkv -> rope'd bf16 Q,K + V^T (bf16)
__global__ __launch_bounds__(256) void prep_qkv2(
    const unsigned short* __restrict__ qkvb, const float* __restrict__ rope,
    __hip_bfloat16* __restrict__ Qb, __hip_bfloat16* __restrict__ Kb,
    __hip_bfloat16* __restrict__ Vtb) {
    int t0 = blockIdx.x * 64;
    int h = blockIdx.y, b = blockIdx.z;
    int bh = b * HH + h;
    int tid = threadIdx.x;
    __shared__ unsigned short vt[64][72];
    int r = tid >> 2, g = tid & 3;
    int t = t0 + r;
    const unsigned short* base = qkvb + (size_t)(b * TT + t) * N1 + h * DD;
    const float* rp = rope + (size_t)t * 64;

    union U8 { uint4 v; unsigned short s[8]; };
    U8 qa, qb2, ka, kb2, va, vb2;
    qa.v  = *(const uint4*)(base + g * 16);
    qb2.v = *(const uint4*)(base + g * 16 + 8);
    ka.v  = *(const uint4*)(base + CC + g * 16);
    kb2.v = *(const uint4*)(base + CC + g * 16 + 8);
    va.v  = *(const uint4*)(base + 2 * CC + g * 16);
    vb2.v = *(const uint4*)(base + 2 * CC + g * 16 + 8);

    U8 qo0, qo1, ko0, ko1;
#pragma unroll
    for (int u = 0; u < 8; ++u) {
        int i = g * 8 + u;              // freq index for local pair u
        float cs = rp[2 * i], sn = rp[2 * i + 1];
        unsigned short uq0 = (u < 4) ? qa.s[2 * u] : qb2.s[2 * u - 8];
        unsigned short uq1 = (u < 4) ? qa.s[2 * u + 1] : qb2.s[2 * u - 7];
        unsigned short uk0 = (u < 4) ? ka.s[2 * u] : kb2.s[2 * u - 8];
        unsigned short uk1 = (u < 4) ? ka.s[2 * u + 1] : kb2.s[2 * u - 7];
        float q0 = bf2f(uq0), q1 = bf2f(uq1);
        float k0 = bf2f(uk0), k1 = bf2f(uk1);
        unsigned int qp = bf16pair((q0 * cs - q1 * sn) * 0.125f, (q1 * cs + q0 * sn) * 0.125f);
        unsigned int kp = bf16pair(k0 * cs - k1 * sn, k1 * cs + k0 * sn);
        if (u < 4) { ((unsigned int*)&qo0)[u] = qp; ((unsigned int*)&ko0)[u] = kp; }
        else       { ((unsigned int*)&qo1)[u - 4] = qp; ((unsigned int*)&ko1)[u - 4] = kp; }
    }
    __hip_bfloat16* qd = Qb + ((size_t)bh * TT + t) * DD + g * 16;
    __hip_bfloat16* kd = Kb + ((size_t)bh * TT + t) * DD + g * 16;
    *(uint4*)(qd) = qo0.v;  *(uint4*)(qd + 8) = qo1.v;
    *(uint4*)(kd) = ko0.v;  *(uint4*)(kd + 8) = ko1.v;

    *(uint4*)(&vt[r][g * 16]) = va.v;
    *(uint4*)(&vt[r][g * 16 + 8]) = vb2.v;
    __syncthreads();
    __hip_bfloat16* vd = Vtb + ((size_t)bh * DD + r) * TT + t0 + g * 16;
#pragma unroll
    for (int u = 0; u < 16; ++u) {
        unsigned short s = vt[g * 16 + u][r];
        vd[u] = *(__hip_bfloat16*)&s;
    }
}

// ------------------------------------------------ barrier-free MFMA attention
// Wave owns 16 q-rows; block = 4 waves = 64 rows; grid 1024 (4 blocks/CU).
// S^T = K·Q^T, O^T = V^T·P^T; P round-trips a wave-private LDS strip.
__global__ __launch_bounds__(256, 4) void attn_mfma3(
    const __hip_bfloat16* __restrict__ Qb, const __hip_bfloat16* __restrict__ Kb,
    const __hip_bfloat16* __restrict__ Vtb,
    __hip_bfloat16* __restrict__ out, float* __restrict__ osq) {
    int idx = blockIdx.x;
    // heavy half first; round-robin gives each CU constant total work
    int qblk = (idx < 512) ? (31 - (idx >> 5)) : ((idx - 512) >> 5);
    int bh = idx & 31;
    int b = bh >> 4, h = bh & 15;
    int tid = threadIdx.x;
    int wave = tid >> 6, lane = tid & 63, quad = lane >> 4, l16 = lane & 15;

    __shared__ __align__(16) unsigned short Ps[4][16 * 72];
    unsigned short* pp = &Ps[wave][0];

    const __hip_bfloat16* Qbase = Qb + (size_t)bh * TT * DD;
    const __hip_bfloat16* Kbase = Kb + (size_t)bh * TT * DD;
    const __hip_bfloat16* Vbase = Vtb + (size_t)bh * DD * TT;

    int qw = qblk * 64 + wave * 16;     // wave's first q row
    short8 qf0, qf1;
    {
        const __hip_bfloat16* qr = Qbase + (size_t)(qw + l16) * DD + quad * 8;
        qf0 = *(const short8*)(qr);
        qf1 = *(const short8*)(qr + 32);
    }
    f32x4 acc_o[4];
#pragma unroll
    for (int mt = 0; mt < 4; ++mt) acc_o[mt] = f32x4{0.f, 0.f, 0.f, 0.f};
    float rs = 0.f;

    for (int kt = 0; kt <= qblk; ++kt) {
        int k0 = kt * 64;
        short8 kf[4][2];
#pragma unroll
        for (int mt = 0; mt < 4; ++mt) {
            const __hip_bfloat16* kr = Kbase + (size_t)(k0 + mt * 16 + l16) * DD + quad * 8;
            kf[mt][0] = *(const short8*)(kr);
            kf[mt][1] = *(const short8*)(kr + 32);
        }
        f32x4 accs[4];
#pragma unroll
        for (int mt = 0; mt < 4; ++mt) {
            f32x4 z = {0.f, 0.f, 0.f, 0.f};
            z = __builtin_amdgcn_mfma_f32_16x16x32_bf16(kf[mt][0], qf0, z, 0, 0, 0);
            accs[mt] = __builtin_amdgcn_mfma_f32_16x16x32_bf16(kf[mt][1], qf1, z, 0, 0, 0);
        }
        short8 vf[4][2];
#pragma unroll
        for (int mt = 0; mt < 4; ++mt) {
            const __hip_bfloat16* vr = Vbase + (size_t)(mt * 16 + l16) * TT + k0 + quad * 8;
            vf[mt][0] = *(const short8*)(vr);
            vf[mt][1] = *(const short8*)(vr + 32);
        }
        bool needmask = (kt == qblk);
        int q_g = qw + l16;
#pragma unroll
        for (int mt = 0; mt < 4; ++mt) {
            int keyb = k0 + mt * 16 + quad * 4;
            float e0 = __expf(accs[mt][0]);
            float e1 = __expf(accs[mt][1]);
            float e2 = __expf(accs[mt][2]);
            float e3 = __expf(accs[mt][3]);
            float p0 = (!needmask || keyb + 0 <= q_g) ? e0 : 0.f;
            float p1 = (!needmask || keyb + 1 <= q_g) ? e1 : 0.f;
            float p2 = (!needmask || keyb + 2 <= q_g) ? e2 : 0.f;
            float p3 = (!needmask || keyb + 3 <= q_g) ? e3 : 0.f;
            rs += p0 + p1 + p2 + p3;
            uint2 w2;
            w2.x = bf16pair(p0, p1);
            w2.y = bf16pair(p2, p3);
            *(uint2*)(pp + l16 * 72 + mt * 16 + quad * 4) = w2;   // P[q=l16][key]
        }
        short8 pf0 = *(const short8*)(pp + l16 * 72 + quad * 8);
        short8 pf1 = *(const short8*)(pp + l16 * 72 + 32 + quad * 8);
#pragma unroll
        for (int mt = 0; mt < 4; ++mt) {
            acc_o[mt] = __builtin_amdgcn_mfma_f32_16x16x32_bf16(vf[mt][0], pf0, acc_o[mt], 0, 0, 0);
            acc_o[mt] = __builtin_amdgcn_mfma_f32_16x16x32_bf16(vf[mt][1], pf1, acc_o[mt], 0, 0, 0);
        }
    }
    // epilogue: normalize, osq, transpose via wave-private LDS strip, store
    rs += __shfl_xor(rs, 16, 64);
    rs += __shfl_xor(rs, 32, 64);
    float inv = 1.f / rs;
    float part = 0.f;
#pragma unroll
    for (int mt = 0; mt < 4; ++mt) {
        float o0 = acc_o[mt][0] * inv;
        float o1 = acc_o[mt][1] * inv;
        float o2 = acc_o[mt][2] * inv;
        float o3 = acc_o[mt][3] * inv;
        part += o0 * o0 + o1 * o1 + o2 * o2 + o3 * o3;
        uint2 w2;
        w2.x = bf16pair(o0, o1);
        w2.y = bf16pair(o2, o3);
        // O[q = l16][d = mt*16 + quad*4 + ri]
        *(uint2*)(pp + l16 * 72 + mt * 16 + quad * 4) = w2;
    }
    part += __shfl_xor(part, 16, 64);
    part += __shfl_xor(part, 32, 64);
    if (quad == 0) atomicAdd(&osq[(size_t)b * TT + qw + l16], part);
    int r = lane >> 2, cg = lane & 3;
    uint4 o0 = *(const uint4*)(pp + r * 72 + cg * 16);
    uint4 o1 = *(const uint4*)(pp + r * 72 + cg * 16 + 8);
    __hip_bfloat16* orow = out + (size_t)(b * TT + qw + r) * CC + h * DD + cg * 16;
    *(uint4*)(orow) = o0;
    *(uint4*)(orow + 8) = o1;
}

// ---------------------------------------------------------------- launcher
extern "C" void kernel_launch(void* const* d_in, const int* in_sizes, int n_in,
                              void* d_out, int out_size, void* d_ws, size_t ws_size,
                              hipStream_t stream) {
    const float* x      = (const float*)d_in[0];
    // d_in[1] = mask (causal tril) — implied analytically, unused
    const float* w_attn = (const float*)d_in[2];
    const float* b_attn = (const float*)d_in[3];
    const float* w_proj = (const float*)d_in[4];
    const float* b_proj = (const float*)d_in[5];
    float* out = (float*)d_out;

    char* ws = (char*)d_ws;
    __hip_bfloat16* qkvb = (__hip_bfloat16*)(ws + 0);         // 4096x3072 bf16 (25165824)
    __hip_bfloat16* xbf  = (__hip_bfloat16*)(ws + 25165824);  // 8 MB
    __hip_bfloat16* aout = (__hip_bfloat16*)(ws + 33554432);  // 8 MB
    __hip_bfloat16* watT = (__hip_bfloat16*)(ws + 41943040);  // 6 MB
    __hip_bfloat16* wpT  = (__hip_bfloat16*)(ws + 48234496);  // 2 MB
    float*          rope = (float*)(ws + 50331648);           // 512 KB
    float*          xsq  = (float*)(ws + 50855936);           // 16 KB
    float*          osq  = (float*)(ws + 50872320);           // 16 KB
    float*          wsqa = (float*)(ws + 50888704);           // 12 KB
    float*          wsqp = (float*)(ws + 50900992);           // 4 KB
    __hip_bfloat16* Qb   = (__hip_bfloat16*)(ws + 50905088);  // 8 MB
    __hip_bfloat16* Kb   = (__hip_bfloat16*)(ws + 59293696);  // 8 MB
    __hip_bfloat16* Vtb  = (__hip_bfloat16*)(ws + 67682304);  // 8 MB

    float scale1 = (float)(sqrt(3072.0) / log1p(3072.0));
    float scale2 = (float)(sqrt(1024.0) / log1p(1024.0));

    hipMemsetAsync(wsqa, 0, 3072 * 4, stream);
    hipMemsetAsync(wsqp, 0, 1024 * 4, stream);
    hipMemsetAsync(osq, 0, ROWS * 4, stream);

    rope_init<<<256, 256, 0, stream>>>(rope);
    rowsq_cast<<<ROWS, 256, 0, stream>>>(x, xsq, xbf);
    transpose_colsq<<<dim3(N1 / 64, CC / 64), 256, 0, stream>>>(w_attn, watT, wsqa, CC, N1);
    transpose_colsq<<<dim3(CC / 64, CC / 64), 256, 0, stream>>>(w_proj, wpT, wsqp, CC, CC);
    yat_gemm_big<128, 128, __hip_bfloat16><<<dim3(N1 / 128, ROWS / 128), 256, 0, stream>>>(
        xbf, watT, xsq, wsqa, b_attn, qkvb, ROWS, N1, CC, scale1);
    prep_qkv2<<<dim3(TT / 64, HH, BB), 256, 0, stream>>>(
        (const unsigned short*)qkvb, rope, Qb, Kb, Vtb);
    attn_mfma3<<<1024, 256, 0, stream>>>(Qb, Kb, Vtb, aout, osq);
    yat_gemm_big<128, 64, float><<<dim3(CC / 64, ROWS / 128), 256, 0, stream>>>(
        aout, wpT, osq, wsqp, b_proj, out, ROWS, CC, CC, scale2);
}

// Round 5
// 318.999 us; speedup vs baseline: 1.0198x; 1.0198x over previous
//
#include <hip/hip_runtime.h>
#include <hip/hip_bf16.h>
#include <cmath>
#include <type_traits>

// Problem constants
#define BB 2
#define TT 2048
#define CC 1024
#define HH 16
#define DD 64
#define ROWS (BB*TT)          // 4096
#define N1 (3*CC)             // 3072
#define EPS 1e-6f

using short8 = __attribute__((ext_vector_type(8))) short;
using f32x4  = __attribute__((ext_vector_type(4))) float;

__device__ __forceinline__ void gl_lds16(const __hip_bfloat16* g, unsigned short* l) {
    __builtin_amdgcn_global_load_lds(
        (const __attribute__((address_space(1))) unsigned int*)(g),
        (__attribute__((address_space(3))) unsigned int*)(l), 16, 0, 0);
}

__device__ __forceinline__ unsigned int bf16pair(float a, float b) {
    __hip_bfloat16 ha = (__hip_bfloat16)a, hb = (__hip_bfloat16)b;  // RNE
    unsigned short ua = *(unsigned short*)&ha, ub = *(unsigned short*)&hb;
    return (unsigned int)ua | ((unsigned int)ub << 16);
}

__device__ __forceinline__ float bf2f(unsigned short u) {
    unsigned int v = (unsigned int)u << 16;
    return *(float*)&v;
}

// ------------------------------- rope table + wsq zero-init (folded memsets)
__global__ void rope_init(float* __restrict__ rope,
                          float* __restrict__ wsqa, float* __restrict__ wsqp) {
    int idx = blockIdx.x * 256 + threadIdx.x;      // 0 .. 65535
    if (idx < N1) wsqa[idx] = 0.f;
    if (idx < CC) wsqp[idx] = 0.f;
    if (idx >= TT * 32) return;
    int t = idx >> 5, i = idx & 31;
    double freq = pow(10000.0, -(double)i / 32.0);
    float ang = (float)t * (float)freq;
    rope[idx * 2 + 0] = cosf(ang);
    rope[idx * 2 + 1] = sinf(ang);
}

// --------------------- row sum-of-squares + bf16 cast (+ osq zero-init)
__global__ void rowsq_cast(const float* __restrict__ X, float* __restrict__ xsq,
                           __hip_bfloat16* __restrict__ Xb, float* __restrict__ osq) {
    int row = blockIdx.x;
    int t = threadIdx.x;
    const float* xr = X + (size_t)row * CC;
    __hip_bfloat16* br = Xb + (size_t)row * CC;
    float p = 0.f;
#pragma unroll
    for (int i = 0; i < 4; ++i) {
        float v = xr[t + i * 256];
        p += v * v;
        br[t + i * 256] = (__hip_bfloat16)v;
    }
    __shared__ float s[256];
    s[t] = p;
    __syncthreads();
    for (int off = 128; off > 0; off >>= 1) {
        if (t < off) s[t] += s[t + off];
        __syncthreads();
    }
    if (t == 0) { xsq[row] = s[0]; osq[row] = 0.f; }
}

// --------------------- transpose W (K x N fp32) -> Wt (N x K bf16) + col sq
__global__ void transpose_colsq(const float* __restrict__ W,
                                __hip_bfloat16* __restrict__ Wt,
                                float* __restrict__ wsq, int K, int N) {
    __shared__ unsigned short tile[64][65];
    int n0 = blockIdx.x * 64, k0 = blockIdx.y * 64;
    int c = threadIdx.x & 63, rg = threadIdx.x >> 6;
    float part = 0.f;
#pragma unroll
    for (int rr = 0; rr < 16; ++rr) {
        int r = rg + rr * 4;
        float f = W[(size_t)(k0 + r) * N + n0 + c];
        __hip_bfloat16 h = (__hip_bfloat16)f;
        tile[r][c] = *(unsigned short*)&h;
        part += f * f;
    }
    atomicAdd(&wsq[n0 + c], part);
    __syncthreads();
#pragma unroll
    for (int rr = 0; rr < 16; ++rr) {
        int r = rg + rr * 4;
        unsigned short u = tile[c][r];
        Wt[(size_t)(n0 + r) * K + k0 + c] = *(__hip_bfloat16*)&u;
    }
}

// ------------------- m97-style MFMA bf16 GEMM (TMxTN tile) with yat epilogue
template<int TM, int TN, typename OutT>
__global__ __launch_bounds__(256) void yat_gemm_big(
    const __hip_bfloat16* __restrict__ A,
    const __hip_bfloat16* __restrict__ Bt,
    const float* __restrict__ xsq, const float* __restrict__ wsq,
    const float* __restrict__ bias, OutT* __restrict__ C,
    int M, int N, int K, float scale) {
    constexpr int MT = TM / 32;
    constexpr int NT = TN / 32;
    constexpr int IA = TM / 64;
    constexpr int IB = TN / 64;
    __shared__ __align__(16) unsigned short As[TM * 32];
    __shared__ __align__(16) unsigned short Bs[TN * 32];
    int tid = threadIdx.x;
    int wave = tid >> 6, lane = tid & 63, quad = lane >> 4, l16 = lane & 15;
    int wr = wave >> 1, wc = wave & 1;
    int m0 = blockIdx.y * TM, n0 = blockIdx.x * TN;

    f32x4 acc[MT][NT];
#pragma unroll
    for (int mt = 0; mt < MT; ++mt)
#pragma unroll
        for (int nt = 0; nt < NT; ++nt) acc[mt][nt] = f32x4{0.f, 0.f, 0.f, 0.f};

    int lrow = lane >> 2, lk = (lane & 3) << 3;
    for (int k0 = 0; k0 < K; k0 += 32) {
        __syncthreads();
#pragma unroll
        for (int i = 0; i < IA; ++i)
            gl_lds16(A + (size_t)(m0 + (wave * IA + i) * 16 + lrow) * K + k0 + lk,
                     As + (wave * IA + i) * 512);
#pragma unroll
        for (int i = 0; i < IB; ++i)
            gl_lds16(Bt + (size_t)(n0 + (wave * IB + i) * 16 + lrow) * K + k0 + lk,
                     Bs + (wave * IB + i) * 512);
        __syncthreads();
        short8 af[MT], bf[NT];
#pragma unroll
        for (int mt = 0; mt < MT; ++mt)
            af[mt] = *(const short8*)(As + (wr * (TM / 2) + mt * 16 + l16) * 32 + quad * 8);
#pragma unroll
        for (int nt = 0; nt < NT; ++nt)
            bf[nt] = *(const short8*)(Bs + (wc * (TN / 2) + nt * 16 + l16) * 32 + quad * 8);
#pragma unroll
        for (int mt = 0; mt < MT; ++mt)
#pragma unroll
            for (int nt = 0; nt < NT; ++nt)
                acc[mt][nt] = __builtin_amdgcn_mfma_f32_16x16x32_bf16(af[mt], bf[nt], acc[mt][nt], 0, 0, 0);
    }
    int mb = m0 + wr * (TM / 2) + quad * 4;
#pragma unroll
    for (int nt = 0; nt < NT; ++nt) {
        int col = n0 + wc * (TN / 2) + nt * 16 + l16;
        float wq = wsq[col];
        float bs = bias[col];
#pragma unroll
        for (int mt = 0; mt < MT; ++mt) {
#pragma unroll
            for (int r = 0; r < 4; ++r) {
                int row = mb + mt * 16 + r;
                float dot = acc[mt][nt][r];
                float dist = xsq[row] + wq - 2.f * dot + EPS;
                C[(size_t)row * N + col] = (OutT)(dot * dot / dist * scale + bs);
            }
        }
    }
}

// -------------------------- prep: bf16 qkv -> rope'd bf16 Q,K + V^T (bf16)
// Q pre-scale = 1/sqrt(64) * log2(e) so attention can use exp2 directly.
__global__ __launch_bounds__(256) void prep_qkv2(
    const unsigned short* __restrict__ qkvb, const float* __restrict__ rope,
    __hip_bfloat16* __restrict__ Qb, __hip_bfloat16* __restrict__ Kb,
    __hip_bfloat16* __restrict__ Vtb) {
    const float QSC = 0.125f * 1.44269504f;
    int t0 = blockIdx.x * 64;
    int h = blockIdx.y, b = blockIdx.z;
    int bh = b * HH + h;
    int tid = threadIdx.x;
    __shared__ unsigned short vt[64][72];
    int r = tid >> 2, g = tid & 3;
    int t = t0 + r;
    const unsigned short* base = qkvb + (size_t)(b * TT + t) * N1 + h * DD;
    const float* rp = rope + (size_t)t * 64;

    union U8 { uint4 v; unsigned short s[8]; };
    U8 qa, qb2, ka, kb2, va, vb2;
    qa.v  = *(const uint4*)(base + g * 16);
    qb2.v = *(const uint4*)(base + g * 16 + 8);
    ka.v  = *(const uint4*)(base + CC + g * 16);
    kb2.v = *(const uint4*)(base + CC + g * 16 + 8);
    va.v  = *(const uint4*)(base + 2 * CC + g * 16);
    vb2.v = *(const uint4*)(base + 2 * CC + g * 16 + 8);

    U8 qo0, qo1, ko0, ko1;
#pragma unroll
    for (int u = 0; u < 8; ++u) {
        int i = g * 8 + u;              // freq index for local pair u
        float cs = rp[2 * i], sn = rp[2 * i + 1];
        unsigned short uq0 = (u < 4) ? qa.s[2 * u] : qb2.s[2 * u - 8];
        unsigned short uq1 = (u < 4) ? qa.s[2 * u + 1] : qb2.s[2 * u - 7];
        unsigned short uk0 = (u < 4) ? ka.s[2 * u] : kb2.s[2 * u - 8];
        unsigned short uk1 = (u < 4) ? ka.s[2 * u + 1] : kb2.s[2 * u - 7];
        float q0 = bf2f(uq0), q1 = bf2f(uq1);
        float k0 = bf2f(uk0), k1 = bf2f(uk1);
        unsigned int qp = bf16pair((q0 * cs - q1 * sn) * QSC, (q1 * cs + q0 * sn) * QSC);
        unsigned int kp = bf16pair(k0 * cs - k1 * sn, k1 * cs + k0 * sn);
        if (u < 4) { ((unsigned int*)&qo0)[u] = qp; ((unsigned int*)&ko0)[u] = kp; }
        else       { ((unsigned int*)&qo1)[u - 4] = qp; ((unsigned int*)&ko1)[u - 4] = kp; }
    }
    __hip_bfloat16* qd = Qb + ((size_t)bh * TT + t) * DD + g * 16;
    __hip_bfloat16* kd = Kb + ((size_t)bh * TT + t) * DD + g * 16;
    *(uint4*)(qd) = qo0.v;  *(uint4*)(qd + 8) = qo1.v;
    *(uint4*)(kd) = ko0.v;  *(uint4*)(kd + 8) = ko1.v;

    *(uint4*)(&vt[r][g * 16]) = va.v;
    *(uint4*)(&vt[r][g * 16 + 8]) = vb2.v;
    __syncthreads();
    // coalesced V^T store: thread owns (d = tid>>3 [+32], t chunk of 8)
#pragma unroll
    for (int p = 0; p < 2; ++p) {
        int d = (tid >> 3) + p * 32;
        int tl = (tid & 7) * 8;
        U8 w;
#pragma unroll
        for (int j = 0; j < 8; ++j) w.s[j] = vt[tl + j][d];
        *(uint4*)(Vtb + ((size_t)bh * DD + d) * TT + t0 + tl) = w.v;
    }
}

// ------------------------------------------------ barrier-free MFMA attention
// Wave owns 16 q-rows; block = 4 waves = 64 rows; grid 1024.
// S^T = K·Q^T, O^T = V^T·P^T; P round-trips a wave-private LDS strip.
// Row sums via all-ones A-fragment MFMA. Diagonal tile split out of main loop.
__global__ __launch_bounds__(256, 3) void attn_mfma4(
    const __hip_bfloat16* __restrict__ Qb, const __hip_bfloat16* __restrict__ Kb,
    const __hip_bfloat16* __restrict__ Vtb,
    __hip_bfloat16* __restrict__ out, float* __restrict__ osq) {
    int idx = blockIdx.x;
    int j = idx >> 5, bh = idx & 31;
    // CU c gets qblks {31-a, 23-a, a, 8+a}: constant total work per CU
    int qblk = (j < 16) ? (31 - j) : (j - 16);
    int b = bh >> 4, h = bh & 15;
    int tid = threadIdx.x;
    int wave = tid >> 6, lane = tid & 63, quad = lane >> 4, l16 = lane & 15;

    __shared__ __align__(16) unsigned short Ps[4][16 * 72];
    unsigned short* pp = &Ps[wave][0];

    const __hip_bfloat16* Qbase = Qb + (size_t)bh * TT * DD;
    const __hip_bfloat16* Kbase = Kb + (size_t)bh * TT * DD;
    const __hip_bfloat16* Vbase = Vtb + (size_t)bh * DD * TT;

    int qw = qblk * 64 + wave * 16;     // wave's first q row
    short8 qf0, qf1;
    {
        const __hip_bfloat16* qr = Qbase + (size_t)(qw + l16) * DD + quad * 8;
        qf0 = *(const short8*)(qr);
        qf1 = *(const short8*)(qr + 32);
    }
    short8 ones8;
#pragma unroll
    for (int i = 0; i < 8; ++i) ones8[i] = (short)0x3F80;   // bf16 1.0

    f32x4 acc_o[4];
#pragma unroll
    for (int mt = 0; mt < 4; ++mt) acc_o[mt] = f32x4{0.f, 0.f, 0.f, 0.f};
    f32x4 acc_l = {0.f, 0.f, 0.f, 0.f};

    auto tile = [&](int k0, auto mc) {
        constexpr bool MASK = decltype(mc)::value;
        short8 kf[4][2], vf[4][2];
#pragma unroll
        for (int mt = 0; mt < 4; ++mt) {
            const __hip_bfloat16* kr = Kbase + (size_t)(k0 + mt * 16 + l16) * DD + quad * 8;
            kf[mt][0] = *(const short8*)(kr);
            kf[mt][1] = *(const short8*)(kr + 32);
        }
#pragma unroll
        for (int mt = 0; mt < 4; ++mt) {
            const __hip_bfloat16* vr = Vbase + (size_t)(mt * 16 + l16) * TT + k0 + quad * 8;
            vf[mt][0] = *(const short8*)(vr);
            vf[mt][1] = *(const short8*)(vr + 32);
        }
        f32x4 accs[4];
#pragma unroll
        for (int mt = 0; mt < 4; ++mt) {
            f32x4 z = {0.f, 0.f, 0.f, 0.f};
            z = __builtin_amdgcn_mfma_f32_16x16x32_bf16(kf[mt][0], qf0, z, 0, 0, 0);
            accs[mt] = __builtin_amdgcn_mfma_f32_16x16x32_bf16(kf[mt][1], qf1, z, 0, 0, 0);
        }
        int q_g = qw + l16;
#pragma unroll
        for (int mt = 0; mt < 4; ++mt) {
            int keyb = k0 + mt * 16 + quad * 4;
            float p0 = exp2f(accs[mt][0]);
            float p1 = exp2f(accs[mt][1]);
            float p2 = exp2f(accs[mt][2]);
            float p3 = exp2f(accs[mt][3]);
            if (MASK) {
                p0 = (keyb + 0 <= q_g) ? p0 : 0.f;
                p1 = (keyb + 1 <= q_g) ? p1 : 0.f;
                p2 = (keyb + 2 <= q_g) ? p2 : 0.f;
                p3 = (keyb + 3 <= q_g) ? p3 : 0.f;
            }
            uint2 w2;
            w2.x = bf16pair(p0, p1);
            w2.y = bf16pair(p2, p3);
            *(uint2*)(pp + l16 * 72 + mt * 16 + quad * 4) = w2;   // P[q=l16][key]
        }
        short8 pf0 = *(const short8*)(pp + l16 * 72 + quad * 8);
        short8 pf1 = *(const short8*)(pp + l16 * 72 + 32 + quad * 8);
#pragma unroll
        for (int mt = 0; mt < 4; ++mt) {
            acc_o[mt] = __builtin_amdgcn_mfma_f32_16x16x32_bf16(vf[mt][0], pf0, acc_o[mt], 0, 0, 0);
            acc_o[mt] = __builtin_amdgcn_mfma_f32_16x16x32_bf16(vf[mt][1], pf1, acc_o[mt], 0, 0, 0);
        }
        acc_l = __builtin_amdgcn_mfma_f32_16x16x32_bf16(ones8, pf0, acc_l, 0, 0, 0);
        acc_l = __builtin_amdgcn_mfma_f32_16x16x32_bf16(ones8, pf1, acc_l, 0, 0, 0);
    };

    for (int kt = 0; kt < qblk; ++kt)
        tile(kt * 64, std::integral_constant<bool, false>{});
    tile(qblk * 64, std::integral_constant<bool, true>{});

    // epilogue: normalize (row sum from acc_l), osq, transpose via LDS, store
    float inv = 1.f / acc_l[0];
    float part = 0.f;
#pragma unroll
    for (int mt = 0; mt < 4; ++mt) {
        float o0 = acc_o[mt][0] * inv;
        float o1 = acc_o[mt][1] * inv;
        float o2 = acc_o[mt][2] * inv;
        float o3 = acc_o[mt][3] * inv;
        part += o0 * o0 + o1 * o1 + o2 * o2 + o3 * o3;
        uint2 w2;
        w2.x = bf16pair(o0, o1);
        w2.y = bf16pair(o2, o3);
        // O[q = l16][d = mt*16 + quad*4 + ri]
        *(uint2*)(pp + l16 * 72 + mt * 16 + quad * 4) = w2;
    }
    part += __shfl_xor(part, 16, 64);
    part += __shfl_xor(part, 32, 64);
    if (quad == 0) atomicAdd(&osq[(size_t)b * TT + qw + l16], part);
    int r = lane >> 2, cg = lane & 3;
    uint4 o0 = *(const uint4*)(pp + r * 72 + cg * 16);
    uint4 o1 = *(const uint4*)(pp + r * 72 + cg * 16 + 8);
    __hip_bfloat16* orow = out + (size_t)(b * TT + qw + r) * CC + h * DD + cg * 16;
    *(uint4*)(orow) = o0;
    *(uint4*)(orow + 8) = o1;
}

// ---------------------------------------------------------------- launcher
extern "C" void kernel_launch(void* const* d_in, const int* in_sizes, int n_in,
                              void* d_out, int out_size, void* d_ws, size_t ws_size,
                              hipStream_t stream) {
    const float* x      = (const float*)d_in[0];
    // d_in[1] = mask (causal tril) — implied analytically, unused
    const float* w_attn = (const float*)d_in[2];
    const float* b_attn = (const float*)d_in[3];
    const float* w_proj = (const float*)d_in[4];
    const float* b_proj = (const float*)d_in[5];
    float* out = (float*)d_out;

    char* ws = (char*)d_ws;
    __hip_bfloat16* qkvb = (__hip_bfloat16*)(ws + 0);         // 4096x3072 bf16
    __hip_bfloat16* xbf  = (__hip_bfloat16*)(ws + 25165824);  // 8 MB
    __hip_bfloat16* aout = (__hip_bfloat16*)(ws + 33554432);  // 8 MB
    __hip_bfloat16* watT = (__hip_bfloat16*)(ws + 41943040);  // 6 MB
    __hip_bfloat16* wpT  = (__hip_bfloat16*)(ws + 48234496);  // 2 MB
    float*          rope = (float*)(ws + 50331648);           // 512 KB
    float*          xsq  = (float*)(ws + 50855936);           // 16 KB
    float*          osq  = (float*)(ws + 50872320);           // 16 KB
    float*          wsqa = (float*)(ws + 50888704);           // 12 KB
    float*          wsqp = (float*)(ws + 50900992);           // 4 KB
    __hip_bfloat16* Qb   = (__hip_bfloat16*)(ws + 50905088);  // 8 MB
    __hip_bfloat16* Kb   = (__hip_bfloat16*)(ws + 59293696);  // 8 MB
    __hip_bfloat16* Vtb  = (__hip_bfloat16*)(ws + 67682304);  // 8 MB

    float scale1 = (float)(sqrt(3072.0) / log1p(3072.0));
    float scale2 = (float)(sqrt(1024.0) / log1p(1024.0));

    rope_init<<<256, 256, 0, stream>>>(rope, wsqa, wsqp);
    rowsq_cast<<<ROWS, 256, 0, stream>>>(x, xsq, xbf, osq);
    transpose_colsq<<<dim3(N1 / 64, CC / 64), 256, 0, stream>>>(w_attn, watT, wsqa, CC, N1);
    transpose_colsq<<<dim3(CC / 64, CC / 64), 256, 0, stream>>>(w_proj, wpT, wsqp, CC, CC);
    yat_gemm_big<128, 128, __hip_bfloat16><<<dim3(N1 / 128, ROWS / 128), 256, 0, stream>>>(
        xbf, watT, xsq, wsqa, b_attn, qkvb, ROWS, N1, CC, scale1);
    prep_qkv2<<<dim3(TT / 64, HH, BB), 256, 0, stream>>>(
        (const unsigned short*)qkvb, rope, Qb, Kb, Vtb);
    attn_mfma4<<<1024, 256, 0, stream>>>(Qb, Kb, Vtb, aout, osq);
    yat_gemm_big<128, 64, float><<<dim3(CC / 64, ROWS / 128), 256, 0, stream>>>(
        aout, wpT, osq, wsqp, b_proj, out, ROWS, CC, CC, scale2);
}

// Round 6
// 318.276 us; speedup vs baseline: 1.0221x; 1.0023x over previous
//
#include <hip/hip_runtime.h>
#include <hip/hip_bf16.h>
#include <cmath>

// Problem constants
#define BB 2
#define TT 2048
#define CC 1024
#define HH 16
#define DD 64
#define ROWS (BB*TT)          // 4096
#define N1 (3*CC)             // 3072
#define EPS 1e-6f

using short8 = __attribute__((ext_vector_type(8))) short;
using f32x4  = __attribute__((ext_vector_type(4))) float;

__device__ __forceinline__ void gl_lds16(const __hip_bfloat16* g, unsigned short* l) {
    __builtin_amdgcn_global_load_lds(
        (const __attribute__((address_space(1))) unsigned int*)(g),
        (__attribute__((address_space(3))) unsigned int*)(l), 16, 0, 0);
}

__device__ __forceinline__ unsigned int bf16pair(float a, float b) {
    __hip_bfloat16 ha = (__hip_bfloat16)a, hb = (__hip_bfloat16)b;  // RNE
    unsigned short ua = *(unsigned short*)&ha, ub = *(unsigned short*)&hb;
    return (unsigned int)ua | ((unsigned int)ub << 16);
}

__device__ __forceinline__ float bf2f(unsigned short u) {
    unsigned int v = (unsigned int)u << 16;
    return *(float*)&v;
}

// ------------------------------- rope table + wsq zero-init (folded memsets)
__global__ void rope_init(float* __restrict__ rope,
                          float* __restrict__ wsqa, float* __restrict__ wsqp) {
    int idx = blockIdx.x * 256 + threadIdx.x;      // 0 .. 65535
    if (idx < N1) wsqa[idx] = 0.f;
    if (idx < CC) wsqp[idx] = 0.f;
    if (idx >= TT * 32) return;
    int t = idx >> 5, i = idx & 31;
    double freq = pow(10000.0, -(double)i / 32.0);
    float ang = (float)t * (float)freq;
    rope[idx * 2 + 0] = cosf(ang);
    rope[idx * 2 + 1] = sinf(ang);
}

// --------------------- row sum-of-squares + bf16 cast (+ osq zero-init)
__global__ void rowsq_cast(const float* __restrict__ X, float* __restrict__ xsq,
                           __hip_bfloat16* __restrict__ Xb, float* __restrict__ osq) {
    int row = blockIdx.x;
    int t = threadIdx.x;
    const float* xr = X + (size_t)row * CC;
    __hip_bfloat16* br = Xb + (size_t)row * CC;
    float p = 0.f;
#pragma unroll
    for (int i = 0; i < 4; ++i) {
        float v = xr[t + i * 256];
        p += v * v;
        br[t + i * 256] = (__hip_bfloat16)v;
    }
    __shared__ float s[256];
    s[t] = p;
    __syncthreads();
    for (int off = 128; off > 0; off >>= 1) {
        if (t < off) s[t] += s[t + off];
        __syncthreads();
    }
    if (t == 0) { xsq[row] = s[0]; osq[row] = 0.f; }
}

// --------------------- transpose W (K x N fp32) -> Wt (N x K bf16) + col sq
__global__ void transpose_colsq(const float* __restrict__ W,
                                __hip_bfloat16* __restrict__ Wt,
                                float* __restrict__ wsq, int K, int N) {
    __shared__ unsigned short tile[64][65];
    int n0 = blockIdx.x * 64, k0 = blockIdx.y * 64;
    int c = threadIdx.x & 63, rg = threadIdx.x >> 6;
    float part = 0.f;
#pragma unroll
    for (int rr = 0; rr < 16; ++rr) {
        int r = rg + rr * 4;
        float f = W[(size_t)(k0 + r) * N + n0 + c];
        __hip_bfloat16 h = (__hip_bfloat16)f;
        tile[r][c] = *(unsigned short*)&h;
        part += f * f;
    }
    atomicAdd(&wsq[n0 + c], part);
    __syncthreads();
#pragma unroll
    for (int rr = 0; rr < 16; ++rr) {
        int r = rg + rr * 4;
        unsigned short u = tile[c][r];
        Wt[(size_t)(n0 + r) * K + k0 + c] = *(__hip_bfloat16*)&u;
    }
}

// ------------------- m97-style MFMA bf16 GEMM (TMxTN tile) with yat epilogue
template<int TM, int TN, typename OutT>
__global__ __launch_bounds__(256) void yat_gemm_big(
    const __hip_bfloat16* __restrict__ A,
    const __hip_bfloat16* __restrict__ Bt,
    const float* __restrict__ xsq, const float* __restrict__ wsq,
    const float* __restrict__ bias, OutT* __restrict__ C,
    int M, int N, int K, float scale) {
    constexpr int MT = TM / 32;
    constexpr int NT = TN / 32;
    constexpr int IA = TM / 64;
    constexpr int IB = TN / 64;
    __shared__ __align__(16) unsigned short As[TM * 32];
    __shared__ __align__(16) unsigned short Bs[TN * 32];
    int tid = threadIdx.x;
    int wave = tid >> 6, lane = tid & 63, quad = lane >> 4, l16 = lane & 15;
    int wr = wave >> 1, wc = wave & 1;
    int m0 = blockIdx.y * TM, n0 = blockIdx.x * TN;

    f32x4 acc[MT][NT];
#pragma unroll
    for (int mt = 0; mt < MT; ++mt)
#pragma unroll
        for (int nt = 0; nt < NT; ++nt) acc[mt][nt] = f32x4{0.f, 0.f, 0.f, 0.f};

    int lrow = lane >> 2, lk = (lane & 3) << 3;
    for (int k0 = 0; k0 < K; k0 += 32) {
        __syncthreads();
#pragma unroll
        for (int i = 0; i < IA; ++i)
            gl_lds16(A + (size_t)(m0 + (wave * IA + i) * 16 + lrow) * K + k0 + lk,
                     As + (wave * IA + i) * 512);
#pragma unroll
        for (int i = 0; i < IB; ++i)
            gl_lds16(Bt + (size_t)(n0 + (wave * IB + i) * 16 + lrow) * K + k0 + lk,
                     Bs + (wave * IB + i) * 512);
        __syncthreads();
        short8 af[MT], bf[NT];
#pragma unroll
        for (int mt = 0; mt < MT; ++mt)
            af[mt] = *(const short8*)(As + (wr * (TM / 2) + mt * 16 + l16) * 32 + quad * 8);
#pragma unroll
        for (int nt = 0; nt < NT; ++nt)
            bf[nt] = *(const short8*)(Bs + (wc * (TN / 2) + nt * 16 + l16) * 32 + quad * 8);
#pragma unroll
        for (int mt = 0; mt < MT; ++mt)
#pragma unroll
            for (int nt = 0; nt < NT; ++nt)
                acc[mt][nt] = __builtin_amdgcn_mfma_f32_16x16x32_bf16(af[mt], bf[nt], acc[mt][nt], 0, 0, 0);
    }
    int mb = m0 + wr * (TM / 2) + quad * 4;
#pragma unroll
    for (int nt = 0; nt < NT; ++nt) {
        int col = n0 + wc * (TN / 2) + nt * 16 + l16;
        float wq = wsq[col];
        float bs = bias[col];
#pragma unroll
        for (int mt = 0; mt < MT; ++mt) {
#pragma unroll
            for (int r = 0; r < 4; ++r) {
                int row = mb + mt * 16 + r;
                float dot = acc[mt][nt][r];
                float dist = xsq[row] + wq - 2.f * dot + EPS;
                C[(size_t)row * N + col] = (OutT)(dot * dot / dist * scale + bs);
            }
        }
    }
}

// -------------------------- prep: bf16 qkv -> rope'd bf16 Q,K + V^T (bf16)
// Q pre-scale = 1/sqrt(64) * log2(e) so attention can use exp2 directly.
__global__ __launch_bounds__(256) void prep_qkv2(
    const unsigned short* __restrict__ qkvb, const float* __restrict__ rope,
    __hip_bfloat16* __restrict__ Qb, __hip_bfloat16* __restrict__ Kb,
    __hip_bfloat16* __restrict__ Vtb) {
    const float QSC = 0.125f * 1.44269504f;
    int t0 = blockIdx.x * 64;
    int h = blockIdx.y, b = blockIdx.z;
    int bh = b * HH + h;
    int tid = threadIdx.x;
    __shared__ unsigned short vt[64][72];
    int r = tid >> 2, g = tid & 3;
    int t = t0 + r;
    const unsigned short* base = qkvb + (size_t)(b * TT + t) * N1 + h * DD;
    const float* rp = rope + (size_t)t * 64;

    union U8 { uint4 v; unsigned short s[8]; };
    U8 qa, qb2, ka, kb2, va, vb2;
    qa.v  = *(const uint4*)(base + g * 16);
    qb2.v = *(const uint4*)(base + g * 16 + 8);
    ka.v  = *(const uint4*)(base + CC + g * 16);
    kb2.v = *(const uint4*)(base + CC + g * 16 + 8);
    va.v  = *(const uint4*)(base + 2 * CC + g * 16);
    vb2.v = *(const uint4*)(base + 2 * CC + g * 16 + 8);

    U8 qo0, qo1, ko0, ko1;
#pragma unroll
    for (int u = 0; u < 8; ++u) {
        int i = g * 8 + u;              // freq index for local pair u
        float cs = rp[2 * i], sn = rp[2 * i + 1];
        unsigned short uq0 = (u < 4) ? qa.s[2 * u] : qb2.s[2 * u - 8];
        unsigned short uq1 = (u < 4) ? qa.s[2 * u + 1] : qb2.s[2 * u - 7];
        unsigned short uk0 = (u < 4) ? ka.s[2 * u] : kb2.s[2 * u - 8];
        unsigned short uk1 = (u < 4) ? ka.s[2 * u + 1] : kb2.s[2 * u - 7];
        float q0 = bf2f(uq0), q1 = bf2f(uq1);
        float k0 = bf2f(uk0), k1 = bf2f(uk1);
        unsigned int qp = bf16pair((q0 * cs - q1 * sn) * QSC, (q1 * cs + q0 * sn) * QSC);
        unsigned int kp = bf16pair(k0 * cs - k1 * sn, k1 * cs + k0 * sn);
        if (u < 4) { ((unsigned int*)&qo0)[u] = qp; ((unsigned int*)&ko0)[u] = kp; }
        else       { ((unsigned int*)&qo1)[u - 4] = qp; ((unsigned int*)&ko1)[u - 4] = kp; }
    }
    __hip_bfloat16* qd = Qb + ((size_t)bh * TT + t) * DD + g * 16;
    __hip_bfloat16* kd = Kb + ((size_t)bh * TT + t) * DD + g * 16;
    *(uint4*)(qd) = qo0.v;  *(uint4*)(qd + 8) = qo1.v;
    *(uint4*)(kd) = ko0.v;  *(uint4*)(kd + 8) = ko1.v;

    *(uint4*)(&vt[r][g * 16]) = va.v;
    *(uint4*)(&vt[r][g * 16 + 8]) = vb2.v;
    __syncthreads();
    // coalesced V^T store: thread owns (d = tid>>3 [+32], t chunk of 8)
#pragma unroll
    for (int p = 0; p < 2; ++p) {
        int d = (tid >> 3) + p * 32;
        int tl = (tid & 7) * 8;
        U8 w;
#pragma unroll
        for (int j = 0; j < 8; ++j) w.s[j] = vt[tl + j][d];
        *(uint4*)(Vtb + ((size_t)bh * DD + d) * TT + t0 + tl) = w.v;
    }
}

// ------------------------------------------------ barrier-free MFMA attention
// Wave owns 16 q-rows; block = 4 waves = 64 rows; grid 1024.
// XCD-aware swizzle: blocks dispatch round-robin over 8 XCDs (i&7); each XCD
// serves only bh ≡ xcd (mod 8) -> 4 bh x 768KB = 3MB < 4MB L2 per XCD.
// SW pipeline: next tile's K prefetched into regs during current compute.
__global__ __launch_bounds__(256, 3) void attn_mfma5(
    const __hip_bfloat16* __restrict__ Qb, const __hip_bfloat16* __restrict__ Kb,
    const __hip_bfloat16* __restrict__ Vtb,
    __hip_bfloat16* __restrict__ out, float* __restrict__ osq) {
    int i = blockIdx.x;
    int xcd = i & 7;
    int r0 = i >> 3;                 // 0..127
    int bh = xcd + 8 * (r0 & 3);     // 4 bh per XCD
    int rr = r0 >> 2;                // 0..31
    int v = rr & 7, s = rr >> 3;
    // balanced bijection: per-CU qblk sets {v, 15-v, 16+v, 31-v} sum to 62
    int qblk = (s == 0) ? v : (s == 1) ? (15 - v) : (s == 2) ? (16 + v) : (31 - v);
    int b = bh >> 4, h = bh & 15;
    int tid = threadIdx.x;
    int wave = tid >> 6, lane = tid & 63, quad = lane >> 4, l16 = lane & 15;

    __shared__ __align__(16) unsigned short Ps[4][16 * 72];
    unsigned short* pp = &Ps[wave][0];

    const __hip_bfloat16* Qbase = Qb + (size_t)bh * TT * DD;
    const __hip_bfloat16* Kbase = Kb + (size_t)bh * TT * DD;
    const __hip_bfloat16* Vbase = Vtb + (size_t)bh * DD * TT;

    int qw = qblk * 64 + wave * 16;     // wave's first q row
    short8 qf0, qf1;
    {
        const __hip_bfloat16* qr = Qbase + (size_t)(qw + l16) * DD + quad * 8;
        qf0 = *(const short8*)(qr);
        qf1 = *(const short8*)(qr + 32);
    }
    short8 ones8;
#pragma unroll
    for (int u = 0; u < 8; ++u) ones8[u] = (short)0x3F80;   // bf16 1.0

    f32x4 acc_o[4];
#pragma unroll
    for (int mt = 0; mt < 4; ++mt) acc_o[mt] = f32x4{0.f, 0.f, 0.f, 0.f};
    f32x4 acc_l = {0.f, 0.f, 0.f, 0.f};

    short8 kf[4][2], kn[4][2], vf[4][2];
    const __hip_bfloat16* krb = Kbase + (size_t)l16 * DD + quad * 8;
#pragma unroll
    for (int mt = 0; mt < 4; ++mt) {
        kf[mt][0] = *(const short8*)(krb + mt * 16 * DD);
        kf[mt][1] = *(const short8*)(krb + mt * 16 * DD + 32);
    }
    int q_g = qw + l16;

    for (int kt = 0; kt <= qblk; ++kt) {
        int k0 = kt * 64;
        // prefetch next K tile into kn (covered by this tile's full compute)
        if (kt < qblk) {
            const __hip_bfloat16* krn = krb + (size_t)(k0 + 64) * DD;
#pragma unroll
            for (int mt = 0; mt < 4; ++mt) {
                kn[mt][0] = *(const short8*)(krn + mt * 16 * DD);
                kn[mt][1] = *(const short8*)(krn + mt * 16 * DD + 32);
            }
        }
        // V for current tile (covered by S + exp phases)
#pragma unroll
        for (int mt = 0; mt < 4; ++mt) {
            const __hip_bfloat16* vr = Vbase + (size_t)(mt * 16 + l16) * TT + k0 + quad * 8;
            vf[mt][0] = *(const short8*)(vr);
            vf[mt][1] = *(const short8*)(vr + 32);
        }
        // S^T = K·Q^T on current kf
        f32x4 accs[4];
#pragma unroll
        for (int mt = 0; mt < 4; ++mt) {
            f32x4 z = {0.f, 0.f, 0.f, 0.f};
            z = __builtin_amdgcn_mfma_f32_16x16x32_bf16(kf[mt][0], qf0, z, 0, 0, 0);
            accs[mt] = __builtin_amdgcn_mfma_f32_16x16x32_bf16(kf[mt][1], qf1, z, 0, 0, 0);
        }
        int limit = (kt == qblk) ? q_g : 0x7FFFFFFF;
#pragma unroll
        for (int mt = 0; mt < 4; ++mt) {
            int keyb = k0 + mt * 16 + quad * 4;
            float p0 = exp2f(accs[mt][0]);
            float p1 = exp2f(accs[mt][1]);
            float p2 = exp2f(accs[mt][2]);
            float p3 = exp2f(accs[mt][3]);
            p0 = (keyb + 0 <= limit) ? p0 : 0.f;
            p1 = (keyb + 1 <= limit) ? p1 : 0.f;
            p2 = (keyb + 2 <= limit) ? p2 : 0.f;
            p3 = (keyb + 3 <= limit) ? p3 : 0.f;
            uint2 w2;
            w2.x = bf16pair(p0, p1);
            w2.y = bf16pair(p2, p3);
            *(uint2*)(pp + l16 * 72 + mt * 16 + quad * 4) = w2;   // P[q=l16][key]
        }
        short8 pf0 = *(const short8*)(pp + l16 * 72 + quad * 8);
        short8 pf1 = *(const short8*)(pp + l16 * 72 + 32 + quad * 8);
#pragma unroll
        for (int mt = 0; mt < 4; ++mt) {
            acc_o[mt] = __builtin_amdgcn_mfma_f32_16x16x32_bf16(vf[mt][0], pf0, acc_o[mt], 0, 0, 0);
            acc_o[mt] = __builtin_amdgcn_mfma_f32_16x16x32_bf16(vf[mt][1], pf1, acc_o[mt], 0, 0, 0);
        }
        acc_l = __builtin_amdgcn_mfma_f32_16x16x32_bf16(ones8, pf0, acc_l, 0, 0, 0);
        acc_l = __builtin_amdgcn_mfma_f32_16x16x32_bf16(ones8, pf1, acc_l, 0, 0, 0);
        // rotate prefetched K into place
#pragma unroll
        for (int mt = 0; mt < 4; ++mt) {
            kf[mt][0] = kn[mt][0];
            kf[mt][1] = kn[mt][1];
        }
    }
    // epilogue: normalize (row sum from acc_l), osq, transpose via LDS, store
    float inv = 1.f / acc_l[0];
    float part = 0.f;
#pragma unroll
    for (int mt = 0; mt < 4; ++mt) {
        float o0 = acc_o[mt][0] * inv;
        float o1 = acc_o[mt][1] * inv;
        float o2 = acc_o[mt][2] * inv;
        float o3 = acc_o[mt][3] * inv;
        part += o0 * o0 + o1 * o1 + o2 * o2 + o3 * o3;
        uint2 w2;
        w2.x = bf16pair(o0, o1);
        w2.y = bf16pair(o2, o3);
        // O[q = l16][d = mt*16 + quad*4 + ri]
        *(uint2*)(pp + l16 * 72 + mt * 16 + quad * 4) = w2;
    }
    part += __shfl_xor(part, 16, 64);
    part += __shfl_xor(part, 32, 64);
    if (quad == 0) atomicAdd(&osq[(size_t)b * TT + qw + l16], part);
    int rw = lane >> 2, cg = lane & 3;
    uint4 o0 = *(const uint4*)(pp + rw * 72 + cg * 16);
    uint4 o1 = *(const uint4*)(pp + rw * 72 + cg * 16 + 8);
    __hip_bfloat16* orow = out + (size_t)(b * TT + qw + rw) * CC + h * DD + cg * 16;
    *(uint4*)(orow) = o0;
    *(uint4*)(orow + 8) = o1;
}

// ---------------------------------------------------------------- launcher
extern "C" void kernel_launch(void* const* d_in, const int* in_sizes, int n_in,
                              void* d_out, int out_size, void* d_ws, size_t ws_size,
                              hipStream_t stream) {
    const float* x      = (const float*)d_in[0];
    // d_in[1] = mask (causal tril) — implied analytically, unused
    const float* w_attn = (const float*)d_in[2];
    const float* b_attn = (const float*)d_in[3];
    const float* w_proj = (const float*)d_in[4];
    const float* b_proj = (const float*)d_in[5];
    float* out = (float*)d_out;

    char* ws = (char*)d_ws;
    __hip_bfloat16* qkvb = (__hip_bfloat16*)(ws + 0);         // 4096x3072 bf16
    __hip_bfloat16* xbf  = (__hip_bfloat16*)(ws + 25165824);  // 8 MB
    __hip_bfloat16* aout = (__hip_bfloat16*)(ws + 33554432);  // 8 MB
    __hip_bfloat16* watT = (__hip_bfloat16*)(ws + 41943040);  // 6 MB
    __hip_bfloat16* wpT  = (__hip_bfloat16*)(ws + 48234496);  // 2 MB
    float*          rope = (float*)(ws + 50331648);           // 512 KB
    float*          xsq  = (float*)(ws + 50855936);           // 16 KB
    float*          osq  = (float*)(ws + 50872320);           // 16 KB
    float*          wsqa = (float*)(ws + 50888704);           // 12 KB
    float*          wsqp = (float*)(ws + 50900992);           // 4 KB
    __hip_bfloat16* Qb   = (__hip_bfloat16*)(ws + 50905088);  // 8 MB
    __hip_bfloat16* Kb   = (__hip_bfloat16*)(ws + 59293696);  // 8 MB
    __hip_bfloat16* Vtb  = (__hip_bfloat16*)(ws + 67682304);  // 8 MB

    float scale1 = (float)(sqrt(3072.0) / log1p(3072.0));
    float scale2 = (float)(sqrt(1024.0) / log1p(1024.0));

    rope_init<<<256, 256, 0, stream>>>(rope, wsqa, wsqp);
    rowsq_cast<<<ROWS, 256, 0, stream>>>(x, xsq, xbf, osq);
    transpose_colsq<<<dim3(N1 / 64, CC / 64), 256, 0, stream>>>(w_attn, watT, wsqa, CC, N1);
    transpose_colsq<<<dim3(CC / 64, CC / 64), 256, 0, stream>>>(w_proj, wpT, wsqp, CC, CC);
    yat_gemm_big<128, 128, __hip_bfloat16><<<dim3(N1 / 128, ROWS / 128), 256, 0, stream>>>(
        xbf, watT, xsq, wsqa, b_attn, qkvb, ROWS, N1, CC, scale1);
    prep_qkv2<<<dim3(TT / 64, HH, BB), 256, 0, stream>>>(
        (const unsigned short*)qkvb, rope, Qb, Kb, Vtb);
    attn_mfma5<<<1024, 256, 0, stream>>>(Qb, Kb, Vtb, aout, osq);
    yat_gemm_big<128, 64, float><<<dim3(CC / 64, ROWS / 128), 256, 0, stream>>>(
        aout, wpT, osq, wsqp, b_proj, out, ROWS, CC, CC, scale2);
}

// Round 7
// 246.214 us; speedup vs baseline: 1.3213x; 1.2927x over previous
//
#include <hip/hip_runtime.h>
#include <hip/hip_bf16.h>
#include <cmath>

// Problem constants
#define BB 2
#define TT 2048
#define CC 1024
#define HH 16
#define DD 64
#define ROWS (BB*TT)          // 4096
#define N1 (3*CC)             // 3072
#define EPS 1e-6f

using short8 = __attribute__((ext_vector_type(8))) short;
using f32x4  = __attribute__((ext_vector_type(4))) float;

__device__ __forceinline__ void gl_lds16(const __hip_bfloat16* g, unsigned short* l) {
    __builtin_amdgcn_global_load_lds(
        (const __attribute__((address_space(1))) unsigned int*)(g),
        (__attribute__((address_space(3))) unsigned int*)(l), 16, 0, 0);
}

__device__ __forceinline__ unsigned int bf16pair(float a, float b) {
    __hip_bfloat16 ha = (__hip_bfloat16)a, hb = (__hip_bfloat16)b;  // RNE
    unsigned short ua = *(unsigned short*)&ha, ub = *(unsigned short*)&hb;
    return (unsigned int)ua | ((unsigned int)ub << 16);
}

__device__ __forceinline__ float bf2f(unsigned short u) {
    unsigned int v = (unsigned int)u << 16;
    return *(float*)&v;
}

// ------------------------------- rope table + wsq zero-init (folded memsets)
__global__ void rope_init(float* __restrict__ rope,
                          float* __restrict__ wsqa, float* __restrict__ wsqp) {
    int idx = blockIdx.x * 256 + threadIdx.x;      // 0 .. 65535
    if (idx < N1) wsqa[idx] = 0.f;
    if (idx < CC) wsqp[idx] = 0.f;
    if (idx >= TT * 32) return;
    int t = idx >> 5, i = idx & 31;
    double freq = pow(10000.0, -(double)i / 32.0);
    float ang = (float)t * (float)freq;
    rope[idx * 2 + 0] = cosf(ang);
    rope[idx * 2 + 1] = sinf(ang);
}

// --------------------- row sum-of-squares + bf16 cast (+ osq zero-init)
__global__ void rowsq_cast(const float* __restrict__ X, float* __restrict__ xsq,
                           __hip_bfloat16* __restrict__ Xb, float* __restrict__ osq) {
    int row = blockIdx.x;
    int t = threadIdx.x;
    const float* xr = X + (size_t)row * CC;
    __hip_bfloat16* br = Xb + (size_t)row * CC;
    float p = 0.f;
#pragma unroll
    for (int i = 0; i < 4; ++i) {
        float v = xr[t + i * 256];
        p += v * v;
        br[t + i * 256] = (__hip_bfloat16)v;
    }
    __shared__ float s[256];
    s[t] = p;
    __syncthreads();
    for (int off = 128; off > 0; off >>= 1) {
        if (t < off) s[t] += s[t + off];
        __syncthreads();
    }
    if (t == 0) { xsq[row] = s[0]; osq[row] = 0.f; }
}

// --------------------- transpose W (K x N fp32) -> Wt (N x K bf16) + col sq
__global__ void transpose_colsq(const float* __restrict__ W,
                                __hip_bfloat16* __restrict__ Wt,
                                float* __restrict__ wsq, int K, int N) {
    __shared__ unsigned short tile[64][65];
    int n0 = blockIdx.x * 64, k0 = blockIdx.y * 64;
    int c = threadIdx.x & 63, rg = threadIdx.x >> 6;
    float part = 0.f;
#pragma unroll
    for (int rr = 0; rr < 16; ++rr) {
        int r = rg + rr * 4;
        float f = W[(size_t)(k0 + r) * N + n0 + c];
        __hip_bfloat16 h = (__hip_bfloat16)f;
        tile[r][c] = *(unsigned short*)&h;
        part += f * f;
    }
    atomicAdd(&wsq[n0 + c], part);
    __syncthreads();
#pragma unroll
    for (int rr = 0; rr < 16; ++rr) {
        int r = rg + rr * 4;
        unsigned short u = tile[c][r];
        Wt[(size_t)(n0 + r) * K + k0 + c] = *(__hip_bfloat16*)&u;
    }
}

// ------------------- m97-style MFMA bf16 GEMM (TMxTN tile) with yat epilogue
template<int TM, int TN, typename OutT>
__global__ __launch_bounds__(256) void yat_gemm_big(
    const __hip_bfloat16* __restrict__ A,
    const __hip_bfloat16* __restrict__ Bt,
    const float* __restrict__ xsq, const float* __restrict__ wsq,
    const float* __restrict__ bias, OutT* __restrict__ C,
    int M, int N, int K, float scale) {
    constexpr int MT = TM / 32;
    constexpr int NT = TN / 32;
    constexpr int IA = TM / 64;
    constexpr int IB = TN / 64;
    __shared__ __align__(16) unsigned short As[TM * 32];
    __shared__ __align__(16) unsigned short Bs[TN * 32];
    int tid = threadIdx.x;
    int wave = tid >> 6, lane = tid & 63, quad = lane >> 4, l16 = lane & 15;
    int wr = wave >> 1, wc = wave & 1;
    int m0 = blockIdx.y * TM, n0 = blockIdx.x * TN;

    f32x4 acc[MT][NT];
#pragma unroll
    for (int mt = 0; mt < MT; ++mt)
#pragma unroll
        for (int nt = 0; nt < NT; ++nt) acc[mt][nt] = f32x4{0.f, 0.f, 0.f, 0.f};

    int lrow = lane >> 2, lk = (lane & 3) << 3;
    for (int k0 = 0; k0 < K; k0 += 32) {
        __syncthreads();
#pragma unroll
        for (int i = 0; i < IA; ++i)
            gl_lds16(A + (size_t)(m0 + (wave * IA + i) * 16 + lrow) * K + k0 + lk,
                     As + (wave * IA + i) * 512);
#pragma unroll
        for (int i = 0; i < IB; ++i)
            gl_lds16(Bt + (size_t)(n0 + (wave * IB + i) * 16 + lrow) * K + k0 + lk,
                     Bs + (wave * IB + i) * 512);
        __syncthreads();
        short8 af[MT], bf[NT];
#pragma unroll
        for (int mt = 0; mt < MT; ++mt)
            af[mt] = *(const short8*)(As + (wr * (TM / 2) + mt * 16 + l16) * 32 + quad * 8);
#pragma unroll
        for (int nt = 0; nt < NT; ++nt)
            bf[nt] = *(const short8*)(Bs + (wc * (TN / 2) + nt * 16 + l16) * 32 + quad * 8);
#pragma unroll
        for (int mt = 0; mt < MT; ++mt)
#pragma unroll
            for (int nt = 0; nt < NT; ++nt)
                acc[mt][nt] = __builtin_amdgcn_mfma_f32_16x16x32_bf16(af[mt], bf[nt], acc[mt][nt], 0, 0, 0);
    }
    int mb = m0 + wr * (TM / 2) + quad * 4;
#pragma unroll
    for (int nt = 0; nt < NT; ++nt) {
        int col = n0 + wc * (TN / 2) + nt * 16 + l16;
        float wq = wsq[col];
        float bs = bias[col];
#pragma unroll
        for (int mt = 0; mt < MT; ++mt) {
#pragma unroll
            for (int r = 0; r < 4; ++r) {
                int row = mb + mt * 16 + r;
                float dot = acc[mt][nt][r];
                float dist = xsq[row] + wq - 2.f * dot + EPS;
                C[(size_t)row * N + col] = (OutT)(dot * dot / dist * scale + bs);
            }
        }
    }
}

// -------------------------- prep: bf16 qkv -> rope'd bf16 Q,K + V^T (bf16)
// Q pre-scale = 1/sqrt(64) * log2(e) so attention can use exp2 directly.
__global__ __launch_bounds__(256) void prep_qkv2(
    const unsigned short* __restrict__ qkvb, const float* __restrict__ rope,
    __hip_bfloat16* __restrict__ Qb, __hip_bfloat16* __restrict__ Kb,
    __hip_bfloat16* __restrict__ Vtb) {
    const float QSC = 0.125f * 1.44269504f;
    int t0 = blockIdx.x * 64;
    int h = blockIdx.y, b = blockIdx.z;
    int bh = b * HH + h;
    int tid = threadIdx.x;
    __shared__ unsigned short vt[64][72];
    int r = tid >> 2, g = tid & 3;
    int t = t0 + r;
    const unsigned short* base = qkvb + (size_t)(b * TT + t) * N1 + h * DD;
    const float* rp = rope + (size_t)t * 64;

    union U8 { uint4 v; unsigned short s[8]; };
    U8 qa, qb2, ka, kb2, va, vb2;
    qa.v  = *(const uint4*)(base + g * 16);
    qb2.v = *(const uint4*)(base + g * 16 + 8);
    ka.v  = *(const uint4*)(base + CC + g * 16);
    kb2.v = *(const uint4*)(base + CC + g * 16 + 8);
    va.v  = *(const uint4*)(base + 2 * CC + g * 16);
    vb2.v = *(const uint4*)(base + 2 * CC + g * 16 + 8);

    U8 qo0, qo1, ko0, ko1;
#pragma unroll
    for (int u = 0; u < 8; ++u) {
        int i = g * 8 + u;              // freq index for local pair u
        float cs = rp[2 * i], sn = rp[2 * i + 1];
        unsigned short uq0 = (u < 4) ? qa.s[2 * u] : qb2.s[2 * u - 8];
        unsigned short uq1 = (u < 4) ? qa.s[2 * u + 1] : qb2.s[2 * u - 7];
        unsigned short uk0 = (u < 4) ? ka.s[2 * u] : kb2.s[2 * u - 8];
        unsigned short uk1 = (u < 4) ? ka.s[2 * u + 1] : kb2.s[2 * u - 7];
        float q0 = bf2f(uq0), q1 = bf2f(uq1);
        float k0 = bf2f(uk0), k1 = bf2f(uk1);
        unsigned int qp = bf16pair((q0 * cs - q1 * sn) * QSC, (q1 * cs + q0 * sn) * QSC);
        unsigned int kp = bf16pair(k0 * cs - k1 * sn, k1 * cs + k0 * sn);
        if (u < 4) { ((unsigned int*)&qo0)[u] = qp; ((unsigned int*)&ko0)[u] = kp; }
        else       { ((unsigned int*)&qo1)[u - 4] = qp; ((unsigned int*)&ko1)[u - 4] = kp; }
    }
    __hip_bfloat16* qd = Qb + ((size_t)bh * TT + t) * DD + g * 16;
    __hip_bfloat16* kd = Kb + ((size_t)bh * TT + t) * DD + g * 16;
    *(uint4*)(qd) = qo0.v;  *(uint4*)(qd + 8) = qo1.v;
    *(uint4*)(kd) = ko0.v;  *(uint4*)(kd + 8) = ko1.v;

    *(uint4*)(&vt[r][g * 16]) = va.v;
    *(uint4*)(&vt[r][g * 16 + 8]) = vb2.v;
    __syncthreads();
    // coalesced V^T store: thread owns (d = tid>>3 [+32], t chunk of 8)
#pragma unroll
    for (int p = 0; p < 2; ++p) {
        int d = (tid >> 3) + p * 32;
        int tl = (tid & 7) * 8;
        U8 w;
#pragma unroll
        for (int j = 0; j < 8; ++j) w.s[j] = vt[tl + j][d];
        *(uint4*)(Vtb + ((size_t)bh * DD + d) * TT + t0 + tl) = w.v;
    }
}

// ------------------------------------ LDS-staged MFMA flash attention
// Block = 4 waves, 64 q-rows (16/wave). K/V tiles staged once per block via
// global_load_lds (m97 pattern, [64][32] half-tiles), shared by all 4 waves.
// S^T = K·Q^T, O^T = V^T·P^T; P strip wave-private (no barrier).
__global__ __launch_bounds__(256, 3) void attn_mfma6(
    const __hip_bfloat16* __restrict__ Qb, const __hip_bfloat16* __restrict__ Kb,
    const __hip_bfloat16* __restrict__ Vtb,
    __hip_bfloat16* __restrict__ out, float* __restrict__ osq) {
    int i = blockIdx.x;
    int xcd = i & 7;
    int r0 = i >> 3;                 // 0..127
    int bh = xcd + 8 * (r0 & 3);     // 4 bh per XCD (L2 locality)
    int rr = r0 >> 2;                // 0..31
    int v = rr & 7, s = rr >> 3;
    // balanced qblk sets {v, 15-v, 16+v, 31-v}
    int qblk = (s == 0) ? v : (s == 1) ? (15 - v) : (s == 2) ? (16 + v) : (31 - v);
    int b = bh >> 4, h = bh & 15;
    int tid = threadIdx.x;
    int wave = tid >> 6, lane = tid & 63, quad = lane >> 4, l16 = lane & 15;

    __shared__ __align__(16) unsigned short Ks[2][64 * 32];   // [d-half][key row][32]
    __shared__ __align__(16) unsigned short Vs[2][64 * 32];   // [key-half][d row][32]
    __shared__ __align__(16) unsigned short Ps[4][16 * 72];
    unsigned short* pp = &Ps[wave][0];

    const __hip_bfloat16* Qbase = Qb + (size_t)bh * TT * DD;
    const __hip_bfloat16* Kbase = Kb + (size_t)bh * TT * DD;
    const __hip_bfloat16* Vbase = Vtb + (size_t)bh * DD * TT;

    int qw = qblk * 64 + wave * 16;     // wave's first q row
    short8 qf0, qf1;
    {
        const __hip_bfloat16* qr = Qbase + (size_t)(qw + l16) * DD + quad * 8;
        qf0 = *(const short8*)(qr);
        qf1 = *(const short8*)(qr + 32);
    }
    short8 ones8;
#pragma unroll
    for (int u = 0; u < 8; ++u) ones8[u] = (short)0x3F80;   // bf16 1.0

    f32x4 acc_o[4];
#pragma unroll
    for (int mt = 0; mt < 4; ++mt) acc_o[mt] = f32x4{0.f, 0.f, 0.f, 0.f};
    f32x4 acc_l = {0.f, 0.f, 0.f, 0.f};

    // staging lane mapping: one inst = 16 rows x 32 shorts (1 KB)
    int srow = lane >> 2;              // 0..15
    int soff = (lane & 3) * 8;         // shorts within 32
    int q_g = qw + l16;

    for (int kt = 0; kt <= qblk; ++kt) {
        int k0 = kt * 64;
        __syncthreads();               // previous tile's LDS reads complete
        // K: rows = keys (wave stages its 16), halves = d 0..31 / 32..63
        gl_lds16(Kbase + (size_t)(k0 + wave * 16 + srow) * DD + soff,      &Ks[0][wave * 512]);
        gl_lds16(Kbase + (size_t)(k0 + wave * 16 + srow) * DD + 32 + soff, &Ks[1][wave * 512]);
        // V^T: rows = d (wave stages its 16), halves = keys 0..31 / 32..63
        gl_lds16(Vbase + (size_t)(wave * 16 + srow) * TT + k0 + soff,      &Vs[0][wave * 512]);
        gl_lds16(Vbase + (size_t)(wave * 16 + srow) * TT + k0 + 32 + soff, &Vs[1][wave * 512]);
        __syncthreads();               // staging visible to all waves

        // S^T = K·Q^T: A = K rows (keys), B = Q rows
        f32x4 accs[4];
#pragma unroll
        for (int mt = 0; mt < 4; ++mt) {
            short8 kf0 = *(const short8*)(&Ks[0][(mt * 16 + l16) * 32 + quad * 8]);
            short8 kf1 = *(const short8*)(&Ks[1][(mt * 16 + l16) * 32 + quad * 8]);
            f32x4 z = {0.f, 0.f, 0.f, 0.f};
            z = __builtin_amdgcn_mfma_f32_16x16x32_bf16(kf0, qf0, z, 0, 0, 0);
            accs[mt] = __builtin_amdgcn_mfma_f32_16x16x32_bf16(kf1, qf1, z, 0, 0, 0);
        }
        int limit = (kt == qblk) ? q_g : 0x7FFFFFFF;
#pragma unroll
        for (int mt = 0; mt < 4; ++mt) {
            int keyb = k0 + mt * 16 + quad * 4;
            float p0 = exp2f(accs[mt][0]);
            float p1 = exp2f(accs[mt][1]);
            float p2 = exp2f(accs[mt][2]);
            float p3 = exp2f(accs[mt][3]);
            p0 = (keyb + 0 <= limit) ? p0 : 0.f;
            p1 = (keyb + 1 <= limit) ? p1 : 0.f;
            p2 = (keyb + 2 <= limit) ? p2 : 0.f;
            p3 = (keyb + 3 <= limit) ? p3 : 0.f;
            uint2 w2;
            w2.x = bf16pair(p0, p1);
            w2.y = bf16pair(p2, p3);
            *(uint2*)(pp + l16 * 72 + mt * 16 + quad * 4) = w2;   // P[q=l16][key]
        }
        short8 pf0 = *(const short8*)(pp + l16 * 72 + quad * 8);
        short8 pf1 = *(const short8*)(pp + l16 * 72 + 32 + quad * 8);
        // O^T += V^T·P^T: A = V^T rows (d), halves by key
#pragma unroll
        for (int mt = 0; mt < 4; ++mt) {
            short8 vf0 = *(const short8*)(&Vs[0][(mt * 16 + l16) * 32 + quad * 8]);
            short8 vf1 = *(const short8*)(&Vs[1][(mt * 16 + l16) * 32 + quad * 8]);
            acc_o[mt] = __builtin_amdgcn_mfma_f32_16x16x32_bf16(vf0, pf0, acc_o[mt], 0, 0, 0);
            acc_o[mt] = __builtin_amdgcn_mfma_f32_16x16x32_bf16(vf1, pf1, acc_o[mt], 0, 0, 0);
        }
        acc_l = __builtin_amdgcn_mfma_f32_16x16x32_bf16(ones8, pf0, acc_l, 0, 0, 0);
        acc_l = __builtin_amdgcn_mfma_f32_16x16x32_bf16(ones8, pf1, acc_l, 0, 0, 0);
    }
    // epilogue: normalize (row sum from acc_l), osq, transpose via LDS, store
    float inv = 1.f / acc_l[0];
    float part = 0.f;
#pragma unroll
    for (int mt = 0; mt < 4; ++mt) {
        float o0 = acc_o[mt][0] * inv;
        float o1 = acc_o[mt][1] * inv;
        float o2 = acc_o[mt][2] * inv;
        float o3 = acc_o[mt][3] * inv;
        part += o0 * o0 + o1 * o1 + o2 * o2 + o3 * o3;
        uint2 w2;
        w2.x = bf16pair(o0, o1);
        w2.y = bf16pair(o2, o3);
        // O[q = l16][d = mt*16 + quad*4 + ri]
        *(uint2*)(pp + l16 * 72 + mt * 16 + quad * 4) = w2;
    }
    part += __shfl_xor(part, 16, 64);
    part += __shfl_xor(part, 32, 64);
    if (quad == 0) atomicAdd(&osq[(size_t)b * TT + qw + l16], part);
    int rw = lane >> 2, cg = lane & 3;
    uint4 o0 = *(const uint4*)(pp + rw * 72 + cg * 16);
    uint4 o1 = *(const uint4*)(pp + rw * 72 + cg * 16 + 8);
    __hip_bfloat16* orow = out + (size_t)(b * TT + qw + rw) * CC + h * DD + cg * 16;
    *(uint4*)(orow) = o0;
    *(uint4*)(orow + 8) = o1;
}

// ---------------------------------------------------------------- launcher
extern "C" void kernel_launch(void* const* d_in, const int* in_sizes, int n_in,
                              void* d_out, int out_size, void* d_ws, size_t ws_size,
                              hipStream_t stream) {
    const float* x      = (const float*)d_in[0];
    // d_in[1] = mask (causal tril) — implied analytically, unused
    const float* w_attn = (const float*)d_in[2];
    const float* b_attn = (const float*)d_in[3];
    const float* w_proj = (const float*)d_in[4];
    const float* b_proj = (const float*)d_in[5];
    float* out = (float*)d_out;

    char* ws = (char*)d_ws;
    __hip_bfloat16* qkvb = (__hip_bfloat16*)(ws + 0);         // 4096x3072 bf16
    __hip_bfloat16* xbf  = (__hip_bfloat16*)(ws + 25165824);  // 8 MB
    __hip_bfloat16* aout = (__hip_bfloat16*)(ws + 33554432);  // 8 MB
    __hip_bfloat16* watT = (__hip_bfloat16*)(ws + 41943040);  // 6 MB
    __hip_bfloat16* wpT  = (__hip_bfloat16*)(ws + 48234496);  // 2 MB
    float*          rope = (float*)(ws + 50331648);           // 512 KB
    float*          xsq  = (float*)(ws + 50855936);           // 16 KB
    float*          osq  = (float*)(ws + 50872320);           // 16 KB
    float*          wsqa = (float*)(ws + 50888704);           // 12 KB
    float*          wsqp = (float*)(ws + 50900992);           // 4 KB
    __hip_bfloat16* Qb   = (__hip_bfloat16*)(ws + 50905088);  // 8 MB
    __hip_bfloat16* Kb   = (__hip_bfloat16*)(ws + 59293696);  // 8 MB
    __hip_bfloat16* Vtb  = (__hip_bfloat16*)(ws + 67682304);  // 8 MB

    float scale1 = (float)(sqrt(3072.0) / log1p(3072.0));
    float scale2 = (float)(sqrt(1024.0) / log1p(1024.0));

    rope_init<<<256, 256, 0, stream>>>(rope, wsqa, wsqp);
    rowsq_cast<<<ROWS, 256, 0, stream>>>(x, xsq, xbf, osq);
    transpose_colsq<<<dim3(N1 / 64, CC / 64), 256, 0, stream>>>(w_attn, watT, wsqa, CC, N1);
    transpose_colsq<<<dim3(CC / 64, CC / 64), 256, 0, stream>>>(w_proj, wpT, wsqp, CC, CC);
    yat_gemm_big<128, 128, __hip_bfloat16><<<dim3(N1 / 128, ROWS / 128), 256, 0, stream>>>(
        xbf, watT, xsq, wsqa, b_attn, qkvb, ROWS, N1, CC, scale1);
    prep_qkv2<<<dim3(TT / 64, HH, BB), 256, 0, stream>>>(
        (const unsigned short*)qkvb, rope, Qb, Kb, Vtb);
    attn_mfma6<<<1024, 256, 0, stream>>>(Qb, Kb, Vtb, aout, osq);
    yat_gemm_big<128, 64, float><<<dim3(CC / 64, ROWS / 128), 256, 0, stream>>>(
        aout, wpT, osq, wsqp, b_proj, out, ROWS, CC, CC, scale2);
}